// Round 1
// baseline (594.126 us; speedup 1.0000x reference)
//
#include <hip/hip_runtime.h>
#include <hip/hip_cooperative_groups.h>
#include <math.h>

namespace cg = cooperative_groups;

#define BB 32
#define AA 8400
#define MM 32
#define NCC 80
#define TOPK 13
#define CAP 1024        // max in-gts anchors per gt: E[max] ~820, >7 sigma to exceed 1024
#define NW (AA / 32 + 1)
#define NCHUNK 33       // ceil(AA/256) anchor chunks per batch
#define NTASK (BB * NCHUNK)   // 1056 resolve/score tasks
#define GRID 1024       // == BB*MM; 4 blocks/CU, co-resident (cooperative)

typedef float nfloat4 __attribute__((ext_vector_type(4)));

// LDS union: phase-1 (topk) view vs phase-2/3 (resolve/scores) view.
struct SmemA {                     // ~13.5 KB
    float lval[CAP];
    int   lidx[CAP];
    float oval[CAP];               // NEW: overlap per candidate, carried to resolve
    unsigned int bmask[NW];
    float wv[2][4];                // double-buffered -> 1 barrier/round instead of 2
    int   wi[2][4];
    int   wsum[4];
    int   s_p, s_sel;
    float s_ov[TOPK];
};
struct SmemB {                     // ~9.5 KB
    float sg[MM][8];               // x1,y1,x2,y2,w1h1,atg,sgx,sgy
    int   slab[MM];
    int   smg[MM];
    unsigned int selcol[256];
    float sov[256];                // per-anchor carried overlap (valid iff fg==1)
    float sam[256];                // per-anchor carried align metric (valid iff fg==1)
    float samv[2][256];            // per-task per-anchor amv, persists across grid.sync
    int   smeta[2][256];           // tg | lab<<8 | fg<<16
    float snv[256];
};
union Smem { SmemA a; SmemB b; };

__device__ __forceinline__ void wave_argmax(float& v, int& i) {
    #pragma unroll
    for (int off = 32; off > 0; off >>= 1) {
        float ov = __shfl_xor(v, off, 64);
        int oi = __shfl_xor(i, off, 64);
        if (ov > v || (ov == v && oi < i)) { v = ov; i = oi; }
    }
}

__global__ __launch_bounds__(256, 4) void fused_assign(
        const float* __restrict__ pd_scores, const float* __restrict__ pd_bboxes,
        const float* __restrict__ anc, const int* __restrict__ gt_labels,
        const float* __restrict__ gt_bboxes, const float* __restrict__ mask_gt,
        int* __restrict__ sel_idx, float* __restrict__ sel_ov, float* __restrict__ sel_am,
        float* __restrict__ pos_am, float* __restrict__ pos_ov,
        float* __restrict__ out_bbox, float* __restrict__ out_scores,
        float* __restrict__ out_fg) {
    __shared__ Smem sm;
    const float eps = 1e-7f;
    int tid = threadIdx.x;
    int lane = tid & 63;
    int wid = tid >> 6;

    // ======================= phase 1: per-(b,m) compaction + top-13 =======================
    {
        int bm = blockIdx.x;              // GRID == BB*MM
        int b = bm >> 5;
        if (tid == 0) pos_am[bm] = 0.f;
        if (tid == 1) pos_ov[bm] = 0.f;
        if (tid == 2) sm.a.s_p = 0;
        if (tid == 3) sm.a.s_sel = 0;
        if (tid < 16) sel_idx[bm * 16 + tid] = -1;   // ws poisoned every call; -1 = empty
        if (mask_gt[bm] > 0.f) {          // mg=false row: no selections (block-uniform skip)
            for (int i = tid; i < NW; i += 256) sm.a.bmask[i] = 0u;
            float4 g = reinterpret_cast<const float4*>(gt_bboxes)[bm];

            // pass 1: streaming in-gts test, bits into a register
            const float4* anc4 = reinterpret_cast<const float4*>(anc);
            unsigned long long bits = 0ull;
            int c_t = 0;
            #pragma unroll
            for (int j = 0; j < 17; j++) {
                int e = tid + (j << 8);
                if (e < 4200) {
                    float4 an = anc4[e];
                    float d0 = fminf(fminf(an.x - g.x, an.y - g.y), fminf(g.z - an.x, g.w - an.y));
                    float d1 = fminf(fminf(an.z - g.x, an.w - g.y), fminf(g.z - an.z, g.w - an.w));
                    if (d0 > 1e-9f) { bits |= 1ull << (2 * j);     c_t++; }
                    if (d1 > 1e-9f) { bits |= 1ull << (2 * j + 1); c_t++; }
                }
            }
            // block prefix sum
            int x = c_t;
            #pragma unroll
            for (int off = 1; off < 64; off <<= 1) {
                int y = __shfl_up(x, off, 64);
                if (lane >= off) x += y;
            }
            if (lane == 63) sm.a.wsum[wid] = x;
            __syncthreads();
            int base = 0;
            #pragma unroll
            for (int w = 0; w < 4; w++) if (w < wid) base += sm.a.wsum[w];
            int n_c = min(sm.a.wsum[0] + sm.a.wsum[1] + sm.a.wsum[2] + sm.a.wsum[3], CAP);
            // pass 2: scatter
            {
                int o = base + x - c_t;
                unsigned long long mm_ = bits;
                while (mm_) {
                    int k = __builtin_ctzll(mm_);
                    mm_ &= mm_ - 1ull;
                    int i = 2 * tid + 512 * (k >> 1) + (k & 1);
                    if (o < CAP) sm.a.lidx[o] = i;
                    o++;
                }
            }
            for (int s = n_c + tid; s < CAP; s += 256) { sm.a.lval[s] = -1.f; sm.a.lidx[s] = AA; }
            __syncthreads();

            // phase B: CIoU + score gather for compacted anchors; keep ov in oval[]
            float w1 = g.z - g.x, h1 = g.w - g.y + eps;
            float atg = atanf(w1 / h1);
            float w1h1 = w1 * h1;
            float sgx = g.x + g.z, sgy = g.y + g.w;
            int lab = gt_labels[bm];
            const float4* pbb = reinterpret_cast<const float4*>(pd_bboxes) + (long)b * AA;
            const float* scp = pd_scores + (long)b * AA * NCC + lab;
            int nit = (n_c + 255) >> 8;
            for (int it = 0; it < nit; it++) {
                int s = (it << 8) + tid;
                bool pos = false;
                if (s < n_c) {
                    int i = sm.a.lidx[s];
                    float4 pb = pbb[i];
                    float sc = scp[(long)i * NCC];
                    float w2 = pb.z - pb.x, h2 = pb.w - pb.y + eps;
                    float iw = fmaxf(fminf(g.z, pb.z) - fmaxf(g.x, pb.x), 0.f);
                    float ih = fmaxf(fminf(g.w, pb.w) - fmaxf(g.y, pb.y), 0.f);
                    float inter = iw * ih;
                    float uni = w1h1 + w2 * h2 - inter + eps;
                    float iou = inter / uni;
                    float cw = fmaxf(g.z, pb.z) - fminf(g.x, pb.x);
                    float ch = fmaxf(g.w, pb.w) - fminf(g.y, pb.y);
                    float c2 = cw * cw + ch * ch + eps;
                    float dx = pb.x + pb.z - sgx, dy = pb.y + pb.w - sgy;
                    float rho2 = (dx * dx + dy * dy) * 0.25f;
                    float dv = atanf(w2 / h2) - atg;
                    float v = 0.4052847345693511f * dv * dv;
                    float alpha = v / (v - iou + (1.0f + eps));
                    float cv = iou - (rho2 / c2 + v * alpha);
                    float ov = fmaxf(cv, 0.f);
                    float o2 = ov * ov;
                    float val = sc * o2 * o2 * o2;   // ALPHA=1, BETA=6
                    pos = val > 0.f;
                    sm.a.lval[s] = pos ? val : -1.f;
                    sm.a.oval[s] = ov;
                    if (pos) atomicOr(&sm.a.bmask[i >> 5], 1u << (i & 31));
                }
                unsigned long long pm = __ballot(pos);
                if (lane == 0) atomicAdd(&sm.a.s_p, (int)__popcll(pm));
            }
            __syncthreads();
            int p = sm.a.s_p;

            if (p >= TOPK) {
                float v0 = sm.a.lval[tid], v1 = sm.a.lval[tid + 256], v2 = sm.a.lval[tid + 512], v3 = sm.a.lval[tid + 768];
                int   i0 = sm.a.lidx[tid], i1 = sm.a.lidx[tid + 256], i2 = sm.a.lidx[tid + 512], i3 = sm.a.lidx[tid + 768];
                int mysel = -1; float myval = 0.f;
                for (int k = 0; k < TOPK; k++) {
                    float bv = v0; int bi = i0;
                    if (v1 > bv || (v1 == bv && i1 < bi)) { bv = v1; bi = i1; }
                    if (v2 > bv || (v2 == bv && i2 < bi)) { bv = v2; bi = i2; }
                    if (v3 > bv || (v3 == bv && i3 < bi)) { bv = v3; bi = i3; }
                    wave_argmax(bv, bi);
                    if (lane == 0) { sm.a.wv[k & 1][wid] = bv; sm.a.wi[k & 1][wid] = bi; }
                    __syncthreads();          // single barrier per round (double-buffered wv)
                    float gv = sm.a.wv[k & 1][0]; int gi = sm.a.wi[k & 1][0];
                    #pragma unroll
                    for (int w = 1; w < 4; w++) {
                        float ov = sm.a.wv[k & 1][w]; int oi = sm.a.wi[k & 1][w];
                        if (ov > gv || (ov == gv && oi < gi)) { gv = ov; gi = oi; }
                    }
                    if (tid == k) { mysel = gi; myval = gv; }
                    if (i0 == gi) { v0 = -1.f; sm.a.s_ov[k] = sm.a.oval[tid]; }
                    if (i1 == gi) { v1 = -1.f; sm.a.s_ov[k] = sm.a.oval[tid + 256]; }
                    if (i2 == gi) { v2 = -1.f; sm.a.s_ov[k] = sm.a.oval[tid + 512]; }
                    if (i3 == gi) { v3 = -1.f; sm.a.s_ov[k] = sm.a.oval[tid + 768]; }
                }
                __syncthreads();
                if (tid < TOPK) {
                    sel_idx[bm * 16 + tid] = mysel;
                    sel_am[bm * 16 + tid] = myval;
                    sel_ov[bm * 16 + tid] = sm.a.s_ov[tid];
                }
            } else {
                // all p positives selected, plus (13-p) lowest-index zero anchors
                for (int s = tid; s < n_c; s += 256)
                    if (sm.a.lval[s] > 0.f) {
                        int slot = atomicAdd(&sm.a.s_sel, 1);
                        sel_idx[bm * 16 + slot] = sm.a.lidx[s];
                        sel_ov[bm * 16 + slot] = sm.a.oval[s];
                        sel_am[bm * 16 + slot] = sm.a.lval[s];
                    }
                if (wid == 0) {
                    int need = TOPK - p;
                    for (int base_i = 0; need > 0 && base_i < AA; base_i += 64) {
                        int i = base_i + lane;
                        bool cand = (i < AA) && !((sm.a.bmask[i >> 5] >> (i & 31)) & 1u);
                        unsigned long long wm = __ballot(cand);
                        int take = min(need, (int)__popcll(wm));
                        if (cand && (int)__popcll(wm & ((1ull << lane) - 1ull)) < take) {
                            float2 an = reinterpret_cast<const float2*>(anc)[i];
                            float dmin = fminf(fminf(an.x - g.x, an.y - g.y), fminf(g.z - an.x, g.w - an.y));
                            if (dmin > 1e-9f) {   // in-gts mask applies after selection
                                int slot = atomicAdd(&sm.a.s_sel, 1);
                                sel_idx[bm * 16 + slot] = i;
                                sel_ov[bm * 16 + slot] = 0.f;   // val==0 => ov==0
                                sel_am[bm * 16 + slot] = 0.f;
                            }
                        }
                        need -= take;
                    }
                }
            }
        }
    }
    __threadfence();
    cg::this_grid().sync();

    // ======================= phase 2: per-anchor resolve (1056 tasks) =======================
    for (int task = blockIdx.x; task < NTASK; task += GRID) {
        int tb = task / NCHUNK;
        int chunk = task - tb * NCHUNK;
        int sidx = task >= GRID ? 1 : 0;
        int a0 = chunk << 8;
        if (tid < MM) {
            int gm = tb * MM + tid;
            float4 gg = reinterpret_cast<const float4*>(gt_bboxes)[gm];
            float w1 = gg.z - gg.x, h1 = gg.w - gg.y + eps;
            sm.b.sg[tid][0] = gg.x; sm.b.sg[tid][1] = gg.y; sm.b.sg[tid][2] = gg.z; sm.b.sg[tid][3] = gg.w;
            sm.b.sg[tid][4] = w1 * h1;
            sm.b.sg[tid][5] = atanf(w1 / h1);
            sm.b.sg[tid][6] = gg.x + gg.z;
            sm.b.sg[tid][7] = gg.y + gg.w;
            int lb = gt_labels[gm]; if (lb < 0) lb = 0;
            sm.b.slab[tid] = lb;
            sm.b.smg[tid] = mask_gt[gm] > 0.f ? 1 : 0;
        }
        sm.b.selcol[tid] = 0u;
        __syncthreads();
        const int* sl = sel_idx + tb * MM * 16;
        #pragma unroll
        for (int t = tid; t < MM * 16; t += 256) {
            int e = sl[t];
            if (e >= a0 && e < a0 + 256) {
                atomicOr(&sm.b.selcol[e - a0], 1u << (t >> 4));
                sm.b.sov[e - a0] = sel_ov[tb * MM * 16 + t];   // single writer iff fg==1
                sm.b.sam[e - a0] = sel_am[tb * MM * 16 + t];
            }
        }
        __syncthreads();
        int a = a0 + tid;
        float amv = 0.f; int tg = 0; int fgo = 0;
        if (a < AA) {
            long gidx = (long)tb * AA + a;
            unsigned int sel = sm.b.selcol[tid];
            int fg = __popc(sel);
            float ovt = 0.f;
            if (fg == 1) {
                tg = __ffs(sel) - 1;
                ovt = sm.b.sov[tid];    // carried from phase 1: no CIoU/atan/score recompute
                amv = sm.b.sam[tid];
                fgo = 1;
            } else if (fg > 1) {
                // multi-assigned: first-occurrence argmax of masked overlaps over all m
                float ax = anc[a * 2], ay = anc[a * 2 + 1];
                float4 pb = reinterpret_cast<const float4*>(pd_bboxes)[gidx];
                float w2 = pb.z - pb.x, h2 = pb.w - pb.y + eps;
                float atp = atanf(w2 / h2);
                float w2h2 = w2 * h2;
                float spx = pb.x + pb.z, spy = pb.y + pb.w;
                float bestov = -1.f; int bestm = 0;
                for (int mm_ = 0; mm_ < MM; mm_++) {
                    float gx1 = sm.b.sg[mm_][0], gy1 = sm.b.sg[mm_][1], gx2 = sm.b.sg[mm_][2], gy2 = sm.b.sg[mm_][3];
                    float dmin = fminf(fminf(ax - gx1, ay - gy1), fminf(gx2 - ax, gy2 - ay));
                    float ov = 0.f;
                    if ((dmin > 1e-9f) && sm.b.smg[mm_]) {
                        float iw = fmaxf(fminf(gx2, pb.z) - fmaxf(gx1, pb.x), 0.f);
                        float ih = fmaxf(fminf(gy2, pb.w) - fmaxf(gy1, pb.y), 0.f);
                        float inter = iw * ih;
                        float uni = sm.b.sg[mm_][4] + w2h2 - inter + eps;
                        float iou = inter / uni;
                        float cw = fmaxf(gx2, pb.z) - fminf(gx1, pb.x);
                        float ch = fmaxf(gy2, pb.w) - fminf(gy1, pb.y);
                        float c2 = cw * cw + ch * ch + eps;
                        float dx = spx - sm.b.sg[mm_][6], dy = spy - sm.b.sg[mm_][7];
                        float rho2 = (dx * dx + dy * dy) * 0.25f;
                        float dv = atp - sm.b.sg[mm_][5];
                        float v = 0.4052847345693511f * dv * dv;
                        float alpha = v / (v - iou + (1.0f + eps));
                        ov = fmaxf(iou - (rho2 / c2 + v * alpha), 0.f);
                    }
                    if (ov > bestov) { bestov = ov; bestm = mm_; }
                }
                tg = bestm; ovt = bestov;
                float sc = pd_scores[gidx * NCC + sm.b.slab[tg]];
                float o2 = ovt * ovt;
                amv = sc * o2 * o2 * o2;
                fgo = 1;
            }
            nfloat4 gb = {sm.b.sg[tg][0], sm.b.sg[tg][1], sm.b.sg[tg][2], sm.b.sg[tg][3]};
            __builtin_nontemporal_store(gb, reinterpret_cast<nfloat4*>(out_bbox) + gidx);
            __builtin_nontemporal_store(fgo ? 1.f : 0.f, out_fg + gidx);
            if (fgo) {
                atomicMax((int*)&pos_am[tb * MM + tg], __float_as_int(amv));  // non-neg: int order == float order
                atomicMax((int*)&pos_ov[tb * MM + tg], __float_as_int(ovt));
            }
        }
        sm.b.samv[sidx][tid] = amv;      // persists across grid.sync for score phase
        sm.b.smeta[sidx][tid] = tg | (sm.b.slab[tg] << 8) | (fgo << 16);
        __syncthreads();                 // WAR: next task reinits selcol/sg
    }
    __threadfence();
    cg::this_grid().sync();

    // ======================= phase 3: normalized one-hot scores =======================
    for (int task = blockIdx.x; task < NTASK; task += GRID) {
        int tb = task / NCHUNK;
        int chunk = task - tb * NCHUNK;
        int sidx = task >= GRID ? 1 : 0;
        int a0 = chunk << 8;
        {
            int mt = sm.b.smeta[sidx][tid];
            float nv = 0.f;
            if (mt & (1 << 16)) {
                int tg = mt & 31;
                int bmi = tb * MM + tg;
                nv = sm.b.samv[sidx][tid] * pos_ov[bmi] / (pos_am[bmi] + 1e-9f);
            }
            sm.b.snv[tid] = nv;
        }
        __syncthreads();
        const long base4 = ((long)tb * AA + a0) * (NCC / 4);
        nfloat4* outs4 = reinterpret_cast<nfloat4*>(out_scores);
        #pragma unroll
        for (int idx = tid; idx < 256 * 20; idx += 256) {    // coalesced: idx = al*20 + q
            int al = idx / 20;
            int q = idx - al * 20;
            int aa_ = a0 + al;
            if (aa_ < AA) {
                nfloat4 o = {0.f, 0.f, 0.f, 0.f};
                float nv = sm.b.snv[al];
                int lab = (sm.b.smeta[sidx][al] >> 8) & 127;
                int d = lab - (q << 2);
                if (d == 0) o.x = nv; else if (d == 1) o.y = nv;
                else if (d == 2) o.z = nv; else if (d == 3) o.w = nv;
                __builtin_nontemporal_store(o, outs4 + base4 + idx);
            }
        }
        __syncthreads();                 // WAR on snv before next task
    }
}

// ---------------------------------------------------------------- launch
extern "C" void kernel_launch(void* const* d_in, const int* in_sizes, int n_in,
                              void* d_out, int out_size, void* d_ws, size_t ws_size,
                              hipStream_t stream) {
    const float* pd_scores = (const float*)d_in[0];
    const float* pd_bboxes = (const float*)d_in[1];
    const float* anc       = (const float*)d_in[2];
    const int*   gt_labels = (const int*)d_in[3];
    const float* gt_bboxes = (const float*)d_in[4];
    const float* mask_gt   = (const float*)d_in[5];

    const long nBA = (long)BB * AA;

    char* ws = (char*)d_ws;
    int*   sel_idx = (int*)ws;    ws += (long)BB * MM * 16 * 4;
    float* sel_ov  = (float*)ws;  ws += (long)BB * MM * 16 * 4;
    float* sel_am  = (float*)ws;  ws += (long)BB * MM * 16 * 4;
    float* pos_am  = (float*)ws;  ws += BB * MM * 4;
    float* pos_ov  = (float*)ws;  ws += BB * MM * 4;

    float* out_bbox   = (float*)d_out;            // B*A*4
    float* out_scores = out_bbox + nBA * 4;       // B*A*NC
    float* out_fg     = out_scores + nBA * NCC;   // B*A

    void* args[] = {
        (void*)&pd_scores, (void*)&pd_bboxes, (void*)&anc, (void*)&gt_labels,
        (void*)&gt_bboxes, (void*)&mask_gt,
        (void*)&sel_idx, (void*)&sel_ov, (void*)&sel_am,
        (void*)&pos_am, (void*)&pos_ov,
        (void*)&out_bbox, (void*)&out_scores, (void*)&out_fg
    };
    hipLaunchCooperativeKernel((void*)fused_assign, dim3(GRID), dim3(256), args, 0, stream);
}

// Round 2
// 193.821 us; speedup vs baseline: 3.0653x; 3.0653x over previous
//
#include <hip/hip_runtime.h>
#include <math.h>

#define BB 32
#define AA 8400
#define MM 32
#define NCC 80
#define TOPK 13
#define CAP 1024        // max in-gts anchors per gt: E[max] ~820, >7 sigma to exceed 1024
#define NW (AA / 32 + 1)

typedef float nfloat4 __attribute__((ext_vector_type(4)));   // native vec for nontemporal builtins

// ---------------------------------------------------------------- wave argmax (64-lane, lowest index on tie)
__device__ __forceinline__ void wave_argmax(float& v, int& i) {
    #pragma unroll
    for (int off = 32; off > 0; off >>= 1) {
        float ov = __shfl_xor(v, off, 64);
        int oi = __shfl_xor(i, off, 64);
        if (ov > v || (ov == v && oi < i)) { v = ov; i = oi; }
    }
}

// ---------------------------------------------------------------- K12: compaction + top-13 -> sel lists (+carried ov/am)
__global__ __launch_bounds__(256) void k12_topk(
        const float* __restrict__ pd_scores, const float* __restrict__ pd_bboxes,
        const float* __restrict__ anc, const int* __restrict__ gt_labels,
        const float* __restrict__ gt_bboxes, const float* __restrict__ mask_gt,
        int* __restrict__ sel_idx, float* __restrict__ sel_ov, float* __restrict__ sel_am,
        float* __restrict__ pos_am, float* __restrict__ pos_ov) {
    __shared__ float lval[CAP];
    __shared__ int   lidx[CAP];
    __shared__ float oval[CAP];          // overlap per candidate, carried to k3
    __shared__ unsigned int bmask[NW];   // positivity bitmask (val>0)
    __shared__ float lw[4][TOPK];        // per-wave top-13 value
    __shared__ int   li[4][TOPK];        // per-wave top-13 index
    __shared__ float lo[4][TOPK];        // per-wave top-13 overlap
    __shared__ int   wsum[4];
    __shared__ int   s_p, s_sel;
    const float eps = 1e-7f;
    int bm = blockIdx.x;
    int b = bm >> 5;                 // MM = 32
    int tid = threadIdx.x;
    int lane = tid & 63;
    int wid = tid >> 6;
    if (tid == 0) pos_am[bm] = 0.f;
    if (tid == 1) pos_ov[bm] = 0.f;
    if (tid == 2) s_p = 0;
    if (tid == 3) s_sel = 0;
    if (tid < 16) sel_idx[bm * 16 + tid] = -1;   // ws poisoned every call; -1 = empty slot
    if (!(mask_gt[bm] > 0.f)) return;  // mg=false row -> no selections (tk_idx->0, counts=13->0)

    for (int i = tid; i < NW; i += 256) bmask[i] = 0u;
    float4 g = reinterpret_cast<const float4*>(gt_bboxes)[bm];

    // ---- pass 1: streaming in-gts test, bits into a register (no cross-iteration deps)
    const float4* anc4 = reinterpret_cast<const float4*>(anc);   // 4200 entries, 2 anchors each
    unsigned long long bits = 0ull;
    int c_t = 0;
    #pragma unroll
    for (int j = 0; j < 17; j++) {
        int e = tid + (j << 8);
        if (e < 4200) {
            float4 an = anc4[e];   // anchor 2e=(x,y), anchor 2e+1=(z,w)
            float d0 = fminf(fminf(an.x - g.x, an.y - g.y), fminf(g.z - an.x, g.w - an.y));
            float d1 = fminf(fminf(an.z - g.x, an.w - g.y), fminf(g.z - an.z, g.w - an.w));
            if (d0 > 1e-9f) { bits |= 1ull << (2 * j);     c_t++; }
            if (d1 > 1e-9f) { bits |= 1ull << (2 * j + 1); c_t++; }
        }
    }
    // ---- block prefix sum of c_t (wave scan + 4-way combine)
    int x = c_t;
    #pragma unroll
    for (int off = 1; off < 64; off <<= 1) {
        int y = __shfl_up(x, off, 64);
        if (lane >= off) x += y;
    }
    if (lane == 63) wsum[wid] = x;
    __syncthreads();
    int base = 0;
    #pragma unroll
    for (int w = 0; w < 4; w++) if (w < wid) base += wsum[w];
    int n_c = min(wsum[0] + wsum[1] + wsum[2] + wsum[3], CAP);
    // ---- pass 2: scatter indices from register bitmask
    {
        int o = base + x - c_t;   // exclusive offset
        unsigned long long mm_ = bits;
        while (mm_) {
            int k = __builtin_ctzll(mm_);
            mm_ &= mm_ - 1ull;
            int i = 2 * tid + 512 * (k >> 1) + (k & 1);
            if (o < CAP) lidx[o] = i;
            o++;
        }
    }
    for (int s = n_c + tid; s < CAP; s += 256) { lval[s] = -1.f; lidx[s] = AA; }
    __syncthreads();

    // ---- phase B: CIoU + score gather only for compacted anchors
    float w1 = g.z - g.x, h1 = g.w - g.y + eps;
    float atg = atanf(w1 / h1);
    float w1h1 = w1 * h1;
    float sgx = g.x + g.z, sgy = g.y + g.w;
    int lab = gt_labels[bm];
    const float4* pbb = reinterpret_cast<const float4*>(pd_bboxes) + (long)b * AA;
    const float* scp = pd_scores + (long)b * AA * NCC + lab;
    int nit = (n_c + 255) >> 8;
    for (int it = 0; it < nit; it++) {
        int s = (it << 8) + tid;
        bool pos = false;
        if (s < n_c) {
            int i = lidx[s];
            float4 pb = pbb[i];
            float sc = scp[(long)i * NCC];
            float w2 = pb.z - pb.x, h2 = pb.w - pb.y + eps;
            float iw = fmaxf(fminf(g.z, pb.z) - fmaxf(g.x, pb.x), 0.f);
            float ih = fmaxf(fminf(g.w, pb.w) - fmaxf(g.y, pb.y), 0.f);
            float inter = iw * ih;
            float uni = w1h1 + w2 * h2 - inter + eps;
            float iou = inter / uni;
            float cw = fmaxf(g.z, pb.z) - fminf(g.x, pb.x);
            float ch = fmaxf(g.w, pb.w) - fminf(g.y, pb.y);
            float c2 = cw * cw + ch * ch + eps;
            float dx = pb.x + pb.z - sgx, dy = pb.y + pb.w - sgy;
            float rho2 = (dx * dx + dy * dy) * 0.25f;
            float dv = atanf(w2 / h2) - atg;
            float v = 0.4052847345693511f * dv * dv;
            float alpha = v / (v - iou + (1.0f + eps));
            float cv = iou - (rho2 / c2 + v * alpha);
            float ov = fmaxf(cv, 0.f);
            float o2 = ov * ov;
            float val = sc * o2 * o2 * o2;   // ALPHA=1, BETA=6
            pos = val > 0.f;
            lval[s] = pos ? val : -1.f;      // in-gts but zero metric: not a positive candidate
            oval[s] = ov;
            if (pos) atomicOr(&bmask[i >> 5], 1u << (i & 31));
        }
        unsigned long long pm = __ballot(pos);
        if (lane == 0) atomicAdd(&s_p, (int)__popcll(pm));
    }
    __syncthreads();
    int p = s_p;

    if (p >= TOPK) {
        // ---- per-wave top-13 over this wave's 256 private slots: pure-shfl, ZERO barriers
        int s0 = (wid << 8) + lane;
        float v0 = lval[s0], v1 = lval[s0 + 64], v2 = lval[s0 + 128], v3 = lval[s0 + 192];
        int   i0 = lidx[s0], i1 = lidx[s0 + 64], i2 = lidx[s0 + 128], i3 = lidx[s0 + 192];
        for (int k = 0; k < TOPK; k++) {
            float bv = v0; int bi = i0;
            if (v1 > bv || (v1 == bv && i1 < bi)) { bv = v1; bi = i1; }
            if (v2 > bv || (v2 == bv && i2 < bi)) { bv = v2; bi = i2; }
            if (v3 > bv || (v3 == bv && i3 < bi)) { bv = v3; bi = i3; }
            wave_argmax(bv, bi);
            // owner lane (indices unique): record overlap + invalidate
            if (i0 == bi) { v0 = -1.f; lo[wid][k] = oval[s0]; }
            if (i1 == bi) { v1 = -1.f; lo[wid][k] = oval[s0 + 64]; }
            if (i2 == bi) { v2 = -1.f; lo[wid][k] = oval[s0 + 128]; }
            if (i3 == bi) { v3 = -1.f; lo[wid][k] = oval[s0 + 192]; }
            if (lane == 0) { lw[wid][k] = bv; li[wid][k] = bi; }
        }
        __syncthreads();
        // ---- wave 0: merge 4x13=52 candidates, 13 shfl rounds, ZERO barriers
        if (wid == 0) {
            float mv = -1.f; int mi = AA; float mo = 0.f;
            if (lane < 4 * TOPK) {
                int w = lane / TOPK, k = lane - w * TOPK;
                mv = lw[w][k]; mi = li[w][k]; mo = lo[w][k];
            }
            for (int k = 0; k < TOPK; k++) {
                float bv = mv; int bi = mi;
                wave_argmax(bv, bi);
                if (mi == bi && mv > -1.f) {        // unique owner of this round's winner
                    sel_idx[bm * 16 + k] = bi;
                    sel_am[bm * 16 + k] = bv;
                    sel_ov[bm * 16 + k] = mo;
                    mv = -1.f;
                }
            }
        }
    } else {
        // ---- all p positives selected (append via LDS counter, <=13 hits) ...
        for (int s = tid; s < n_c; s += 256)
            if (lval[s] > 0.f) {
                int slot = atomicAdd(&s_sel, 1);
                sel_idx[bm * 16 + slot] = lidx[s];
                sel_ov[bm * 16 + slot] = oval[s];
                sel_am[bm * 16 + slot] = lval[s];
            }
        // ---- ... plus the 13-p lowest-index zero-valued anchors (ballot windows, wave 0)
        if (wid == 0) {
            int need = TOPK - p;
            for (int base_i = 0; need > 0 && base_i < AA; base_i += 64) {
                int i = base_i + lane;
                bool cand = (i < AA) && !((bmask[i >> 5] >> (i & 31)) & 1u);
                unsigned long long wm = __ballot(cand);
                int take = min(need, (int)__popcll(wm));
                if (cand && (int)__popcll(wm & ((1ull << lane) - 1ull)) < take) {
                    // selected by top_k regardless of in-gts; in-gts mask applies after
                    float2 an = reinterpret_cast<const float2*>(anc)[i];
                    float dmin = fminf(fminf(an.x - g.x, an.y - g.y), fminf(g.z - an.x, g.w - an.y));
                    if (dmin > 1e-9f) {
                        // exact overlap for zero-val filler (sc==0 corner: ov may be >0)
                        float4 pb = pbb[i];
                        float w2 = pb.z - pb.x, h2 = pb.w - pb.y + eps;
                        float iw = fmaxf(fminf(g.z, pb.z) - fmaxf(g.x, pb.x), 0.f);
                        float ih = fmaxf(fminf(g.w, pb.w) - fmaxf(g.y, pb.y), 0.f);
                        float inter = iw * ih;
                        float uni = w1h1 + w2 * h2 - inter + eps;
                        float iou = inter / uni;
                        float cw = fmaxf(g.z, pb.z) - fminf(g.x, pb.x);
                        float ch = fmaxf(g.w, pb.w) - fminf(g.y, pb.y);
                        float c2 = cw * cw + ch * ch + eps;
                        float dx = pb.x + pb.z - sgx, dy = pb.y + pb.w - sgy;
                        float rho2 = (dx * dx + dy * dy) * 0.25f;
                        float dv = atanf(w2 / h2) - atg;
                        float v = 0.4052847345693511f * dv * dv;
                        float alpha = v / (v - iou + (1.0f + eps));
                        float ov = fmaxf(iou - (rho2 / c2 + v * alpha), 0.f);
                        int slot = atomicAdd(&s_sel, 1);
                        sel_idx[bm * 16 + slot] = i;
                        sel_ov[bm * 16 + slot] = ov;
                        sel_am[bm * 16 + slot] = 0.f;   // filler is never a positive
                    }
                }
                need -= take;
            }
        }
    }
}

// ---------------------------------------------------------------- K3: per-anchor column resolve (mask from sel lists)
__global__ __launch_bounds__(256) void k3_resolve(
        const float* __restrict__ pd_scores, const float* __restrict__ pd_bboxes,
        const float* __restrict__ anc, const int* __restrict__ gt_labels,
        const float* __restrict__ gt_bboxes, const float* __restrict__ mask_gt,
        const int* __restrict__ sel_idx, const float* __restrict__ sel_ov,
        const float* __restrict__ sel_am,
        float* __restrict__ pos_am, float* __restrict__ pos_ov,
        float* __restrict__ out_bbox, float* __restrict__ out_fg,
        int2* __restrict__ meta) {
    __shared__ float sg[MM][8];   // x1,y1,x2,y2,w1h1,atg,sgx,sgy
    __shared__ int slab[MM];
    __shared__ int smg[MM];
    __shared__ unsigned int selcol[256];   // per-anchor m-bitmask for this 256-anchor chunk
    __shared__ float sov[256];             // carried overlap (valid iff fg==1)
    __shared__ float sam[256];             // carried align metric (valid iff fg==1)
    const float eps = 1e-7f;
    int b = blockIdx.y;
    int tid = threadIdx.x;
    if (tid < MM) {
        int gm = b * MM + tid;
        float4 g = reinterpret_cast<const float4*>(gt_bboxes)[gm];
        float w1 = g.z - g.x, h1 = g.w - g.y + eps;
        sg[tid][0] = g.x; sg[tid][1] = g.y; sg[tid][2] = g.z; sg[tid][3] = g.w;
        sg[tid][4] = w1 * h1;
        sg[tid][5] = atanf(w1 / h1);
        sg[tid][6] = g.x + g.z;
        sg[tid][7] = g.y + g.w;
        int lb = gt_labels[gm]; if (lb < 0) lb = 0;
        slab[tid] = lb;
        smg[tid] = mask_gt[gm] > 0.f ? 1 : 0;
    }
    selcol[tid] = 0u;
    __syncthreads();
    int a0 = blockIdx.x * 256;
    // build the column mask from this batch's 32 lists (512 entries, 2 iters)
    const int* sl = sel_idx + b * MM * 16;
    #pragma unroll
    for (int t = tid; t < MM * 16; t += 256) {
        int e = sl[t];
        if (e >= a0 && e < a0 + 256) {
            atomicOr(&selcol[e - a0], 1u << (t >> 4));
            sov[e - a0] = sel_ov[b * MM * 16 + t];   // single writer iff fg==1 (only path that reads it)
            sam[e - a0] = sel_am[b * MM * 16 + t];
        }
    }
    __syncthreads();
    int a = a0 + tid;
    if (a >= AA) return;
    int g = b * AA + a;
    unsigned int sel = selcol[tid];
    int fg = __popc(sel);

    int tg = 0; bool fgo = false; float ovt = 0.f; float amv = 0.f;
    if (fg == 1) {
        // single positive: values carried from k12 — no recompute, no gathers
        tg = __ffs(sel) - 1;
        ovt = sov[tid];
        amv = sam[tid];
        fgo = true;
    } else if (fg > 1) {
        // multi-assigned: replace column with first-occurrence argmax of masked overlaps
        float ax = anc[a * 2], ay = anc[a * 2 + 1];
        float4 pb = reinterpret_cast<const float4*>(pd_bboxes)[g];
        float w2 = pb.z - pb.x, h2 = pb.w - pb.y + eps;
        float atp = atanf(w2 / h2);
        float w2h2 = w2 * h2;
        float spx = pb.x + pb.z, spy = pb.y + pb.w;
        float bestov = -1.f; int bestm = 0;
        for (int mm = 0; mm < MM; mm++) {
            float gx1 = sg[mm][0], gy1 = sg[mm][1], gx2 = sg[mm][2], gy2 = sg[mm][3];
            float dmin = fminf(fminf(ax - gx1, ay - gy1), fminf(gx2 - ax, gy2 - ay));
            float ov = 0.f;
            if ((dmin > 1e-9f) && smg[mm]) {
                float iw = fmaxf(fminf(gx2, pb.z) - fmaxf(gx1, pb.x), 0.f);
                float ih = fmaxf(fminf(gy2, pb.w) - fmaxf(gy1, pb.y), 0.f);
                float inter = iw * ih;
                float uni = sg[mm][4] + w2h2 - inter + eps;
                float iou = inter / uni;
                float cw = fmaxf(gx2, pb.z) - fminf(gx1, pb.x);
                float ch = fmaxf(gy2, pb.w) - fminf(gy1, pb.y);
                float c2 = cw * cw + ch * ch + eps;
                float dx = spx - sg[mm][6], dy = spy - sg[mm][7];
                float rho2 = (dx * dx + dy * dy) * 0.25f;
                float dv = atp - sg[mm][5];
                float v = 0.4052847345693511f * dv * dv;
                float alpha = v / (v - iou + (1.0f + eps));
                ov = fmaxf(iou - (rho2 / c2 + v * alpha), 0.f);
            }
            if (ov > bestov) { bestov = ov; bestm = mm; }
        }
        tg = bestm; ovt = bestov;
        float sc = pd_scores[(long)g * NCC + slab[tg]];
        float o2 = ovt * ovt;
        amv = sc * o2 * o2 * o2;
        fgo = true;
    }

    nfloat4 gb = {sg[tg][0], sg[tg][1], sg[tg][2], sg[tg][3]};
    __builtin_nontemporal_store(gb, reinterpret_cast<nfloat4*>(out_bbox) + g);
    out_fg[g] = fgo ? 1.f : 0.f;
    if (fgo) {
        atomicMax((int*)&pos_am[b * MM + tg], __float_as_int(amv));   // non-negative floats: int order == float order
        atomicMax((int*)&pos_ov[b * MM + tg], __float_as_int(ovt));
    }
    meta[g] = make_int2(__float_as_int(amv), tg | (slab[tg] << 8) | ((fgo ? 1 : 0) << 16));
}

// ---------------------------------------------------------------- K4: norm + one-hot target_scores (nontemporal float4)
__global__ __launch_bounds__(256) void k4_scores(
        const int2* __restrict__ meta,
        const float* __restrict__ pos_am, const float* __restrict__ pos_ov,
        float* __restrict__ out_scores) {
    int g = blockIdx.x * 256 + threadIdx.x;
    const int NQ = NCC / 4;   // 20 float4 per (b,a)
    if (g >= BB * AA * NQ) return;
    int ba = g / NQ;
    int c0 = (g % NQ) * 4;
    nfloat4 o = {0.f, 0.f, 0.f, 0.f};
    int2 mt = meta[ba];
    int p = mt.y;
    if (p & (1 << 16)) {
        int tg = p & 31, lab = (p >> 8) & 127;
        int b = ba / AA;
        int bm = b * MM + tg;
        float nv = (__int_as_float(mt.x) * pos_ov[bm]) / (pos_am[bm] + 1e-9f);
        int d = lab - c0;
        if (d == 0) o.x = nv; else if (d == 1) o.y = nv;
        else if (d == 2) o.z = nv; else if (d == 3) o.w = nv;
    }
    __builtin_nontemporal_store(o, reinterpret_cast<nfloat4*>(out_scores) + g);
}

// ---------------------------------------------------------------- launch
extern "C" void kernel_launch(void* const* d_in, const int* in_sizes, int n_in,
                              void* d_out, int out_size, void* d_ws, size_t ws_size,
                              hipStream_t stream) {
    const float* pd_scores = (const float*)d_in[0];
    const float* pd_bboxes = (const float*)d_in[1];
    const float* anc       = (const float*)d_in[2];
    const int*   gt_labels = (const int*)d_in[3];
    const float* gt_bboxes = (const float*)d_in[4];
    const float* mask_gt   = (const float*)d_in[5];

    const long nBA = (long)BB * AA;

    char* ws = (char*)d_ws;
    int*   sel_idx = (int*)ws;                  ws += (long)BB * MM * 16 * 4;
    float* sel_ov  = (float*)ws;                ws += (long)BB * MM * 16 * 4;
    float* sel_am  = (float*)ws;                ws += (long)BB * MM * 16 * 4;
    float* pos_am  = (float*)ws;                ws += BB * MM * 4;
    float* pos_ov  = (float*)ws;                ws += BB * MM * 4;
    int2*  meta    = (int2*)ws;                 ws += nBA * 8;

    float* out_bbox   = (float*)d_out;            // B*A*4
    float* out_scores = out_bbox + nBA * 4;       // B*A*NC
    float* out_fg     = out_scores + nBA * NCC;   // B*A

    k12_topk<<<BB * MM, 256, 0, stream>>>(pd_scores, pd_bboxes, anc, gt_labels,
                                          gt_bboxes, mask_gt, sel_idx, sel_ov, sel_am,
                                          pos_am, pos_ov);
    dim3 g3((AA + 255) / 256, BB);
    k3_resolve<<<g3, 256, 0, stream>>>(pd_scores, pd_bboxes, anc, gt_labels,
                                       gt_bboxes, mask_gt, sel_idx, sel_ov, sel_am,
                                       pos_am, pos_ov, out_bbox, out_fg, meta);
    long nS4 = nBA * (NCC / 4);
    k4_scores<<<(int)((nS4 + 255) / 256), 256, 0, stream>>>(meta, pos_am, pos_ov, out_scores);
}